// Round 5
// baseline (151.428 us; speedup 1.0000x reference)
//
#include <hip/hip_runtime.h>

typedef __bf16 bf16;
typedef bf16 bf16x2 __attribute__((ext_vector_type(2)));
typedef bf16 bf16x4 __attribute__((ext_vector_type(4)));
typedef bf16 bf16x8 __attribute__((ext_vector_type(8)));
typedef float f32x4 __attribute__((ext_vector_type(4)));
typedef float f32x16 __attribute__((ext_vector_type(16)));
typedef unsigned int u32;
typedef u32 u32x4 __attribute__((ext_vector_type(4)));
typedef float4 f4;

constexpr int BHN = 64;   // B*H
constexpr int LN  = 4096;
constexpr int DN  = 64;
constexpr int MN  = 266;  // real feature rows
constexpr int MP  = 320;  // padded to 5*64 (workspace only written for m<MN)
constexpr int STR = 72;   // LDS row stride in bf16 (144B)
constexpr int KVS = 328;  // kv LDS row stride in bf16 (656B)
#define EPSF 1e-3f

#define MFMA32(A, B, C) __builtin_amdgcn_mfma_f32_32x32x16_bf16(A, B, C, 0, 0, 0)

__device__ __forceinline__ u32 cvt_pk_bf16(float lo, float hi) {
  u32 r;
  asm("v_cvt_pk_bf16_f32 %0, %1, %2" : "=v"(r) : "v"(lo), "v"(hi));
  return r;
}

// ---------------------------------------------------------------------------
// Kernel A v2 (32x32 MFMA, no LDS, no barriers):
//   kvT[bh][d][m] += V^T·kp,  ksum[bh][m] += sum_l kp,  kp = relu(K·projT)+eps
// grid (8 l-chunks, 64 bh) x 320 threads (5 waves; wave w owns m in [64w,64w+64))
// Feature C1[l][m] comes out lane=m-col, regs=l-rows; cvt_pk+permlane32_swap
// turns it directly into the kv-MFMA B-operand (col=m, k=l). Proven in B (r4).
// ---------------------------------------------------------------------------
__global__ __launch_bounds__(320, 2) void perf_kv_mfma32(
    const float* __restrict__ kg, const float* __restrict__ vg,
    const float* __restrict__ proj, float* __restrict__ kv_ws,
    float* __restrict__ ksum_ws)
{
  const int t    = threadIdx.x;
  const int wid  = t >> 6;      // 0..4
  const int lane = t & 63;
  const int ln31 = lane & 31;
  const int hi   = lane >> 5;
  const int lsp  = blockIdx.x;  // 0..7
  const int bh   = blockIdx.y;  // 0..63
  const int mw   = wid * 64;

  // proj B-fragments, register-resident: col m = mw+mt*32+ln31, k(d)=ks*16+hi*8+e
  bf16x8 pb[2][4];
#pragma unroll
  for (int mt = 0; mt < 2; ++mt) {
    const int m = mw + mt * 32 + ln31;
#pragma unroll
    for (int ks = 0; ks < 4; ++ks) {
      bf16x8 w = {};
      if (m < MN) {
        const float* p = proj + m * 64 + ks * 16 + hi * 8;
        f4 a = *(const f4*)p;
        f4 b = *(const f4*)(p + 4);
        w = (bf16x8){(bf16)a.x, (bf16)a.y, (bf16)a.z, (bf16)a.w,
                     (bf16)b.x, (bf16)b.y, (bf16)b.z, (bf16)b.w};
      }
      pb[mt][ks] = w;
    }
  }

  f32x16 acc[2][2];  // [dt][mt]: kvT rows d = dt*32 + (r&3)+8(r>>2)+4hi, col m
  acc[0][0] = (f32x16){}; acc[0][1] = (f32x16){};
  acc[1][0] = (f32x16){}; acc[1][1] = (f32x16){};
  float ksum_acc[2] = {0.f, 0.f};

  const float* kbp = kg + ((size_t)bh * LN) * 64;
  const float* vbp = vg + ((size_t)bh * LN) * 64;

  for (int ls = 0; ls < 16; ++ls) {
    const int l0 = lsp * 512 + ls * 32;

    // K A-fragments: row l = l0+ln31, k(d) = ks*16+hi*8+e
    bf16x8 ka[4];
#pragma unroll
    for (int ks = 0; ks < 4; ++ks) {
      const float* p = kbp + (size_t)(l0 + ln31) * 64 + ks * 16 + hi * 8;
      f4 a = *(const f4*)p;
      f4 b = *(const f4*)(p + 4);
      ka[ks] = (bf16x8){(bf16)a.x, (bf16)a.y, (bf16)a.z, (bf16)a.w,
                        (bf16)b.x, (bf16)b.y, (bf16)b.z, (bf16)b.w};
    }
    // V^T A-fragments: row d = dt*32+ln31, k(l) = kk*16+hi*8+e
    bf16x8 va[2][2];
#pragma unroll
    for (int dt = 0; dt < 2; ++dt)
#pragma unroll
      for (int kk = 0; kk < 2; ++kk) {
        float x[8];
#pragma unroll
        for (int e = 0; e < 8; ++e)
          x[e] = vbp[(size_t)(l0 + kk * 16 + hi * 8 + e) * 64 + dt * 32 + ln31];
        va[dt][kk] = (bf16x8){(bf16)x[0], (bf16)x[1], (bf16)x[2], (bf16)x[3],
                              (bf16)x[4], (bf16)x[5], (bf16)x[6], (bf16)x[7]};
      }

    // feature: C1[l][m] = K·projT  (lane = m-col, regs = l-rows)
    f32x16 c1[2];
    c1[0] = (f32x16){}; c1[1] = (f32x16){};
#pragma unroll
    for (int ks = 0; ks < 4; ++ks) {
      c1[0] = MFMA32(ka[ks], pb[0][ks], c1[0]);
      c1[1] = MFMA32(ka[ks], pb[1][ks], c1[1]);
    }

#pragma unroll
    for (int mt = 0; mt < 2; ++mt) {
      f32x16 f = c1[mt];
#pragma unroll
      for (int i = 0; i < 16; ++i) f[i] = fmaxf(f[i], 0.f) + EPSF;
      ksum_acc[mt] += f[0] + f[1] + f[2] + f[3] + f[4] + f[5] + f[6] + f[7]
                    + f[8] + f[9] + f[10] + f[11] + f[12] + f[13] + f[14] + f[15];
      // T12: pack to bf16 words, permlane-swap into B-operand (col=m, k=l) layout
      u32 w0 = cvt_pk_bf16(f[0], f[1]);
      u32 w1 = cvt_pk_bf16(f[2], f[3]);
      u32 w2 = cvt_pk_bf16(f[4], f[5]);
      u32 w3 = cvt_pk_bf16(f[6], f[7]);
      u32 w4 = cvt_pk_bf16(f[8], f[9]);
      u32 w5 = cvt_pk_bf16(f[10], f[11]);
      u32 w6 = cvt_pk_bf16(f[12], f[13]);
      u32 w7 = cvt_pk_bf16(f[14], f[15]);
      asm("v_permlane32_swap_b32 %0, %1" : "+v"(w0), "+v"(w2));
      asm("v_permlane32_swap_b32 %0, %1" : "+v"(w1), "+v"(w3));
      asm("v_permlane32_swap_b32 %0, %1" : "+v"(w4), "+v"(w6));
      asm("v_permlane32_swap_b32 %0, %1" : "+v"(w5), "+v"(w7));
      u32x4 a0 = {w0, w1, w2, w3};
      u32x4 a1 = {w4, w5, w6, w7};
      bf16x8 kb0 = __builtin_bit_cast(bf16x8, a0);  // k = l rel 0..15
      bf16x8 kb1 = __builtin_bit_cast(bf16x8, a1);  // k = l rel 16..31
      acc[0][mt] = MFMA32(va[0][0], kb0, acc[0][mt]);
      acc[1][mt] = MFMA32(va[1][0], kb0, acc[1][mt]);
      acc[0][mt] = MFMA32(va[0][1], kb1, acc[0][mt]);
      acc[1][mt] = MFMA32(va[1][1], kb1, acc[1][mt]);
    }
  }

  // epilogue: f32 atomics into workspace (guarded: padded m stays exactly 0)
#pragma unroll
  for (int mt = 0; mt < 2; ++mt) {
    const int m = mw + mt * 32 + ln31;
    if (m < MN) {
#pragma unroll
      for (int dt = 0; dt < 2; ++dt) {
#pragma unroll
        for (int r = 0; r < 16; ++r) {
          const int d = dt * 32 + (r & 3) + 8 * (r >> 2) + 4 * hi;
          atomicAdd(&kv_ws[((size_t)bh * 64 + d) * MP + m], acc[dt][mt][r]);
        }
      }
    }
    float r = ksum_acc[mt];
    r += __shfl_xor(r, 32);
    if (hi == 0 && m < MN) atomicAdd(&ksum_ws[bh * MP + m], r);
  }
}

// ---------------------------------------------------------------------------
// Kernel C: one-shot f32 -> bf16 conversion of kv workspace and proj
// ---------------------------------------------------------------------------
__global__ __launch_bounds__(256) void perf_cvt(
    const float* __restrict__ kv_ws, const float* __restrict__ proj,
    bf16* __restrict__ kv_b, bf16* __restrict__ pj_b)
{
  const int KV4 = BHN * DN * MP / 4;  // 327680
  const int PJ4 = MP * DN / 4;        // 5120
  int idx = blockIdx.x * 256 + threadIdx.x;
  if (idx < KV4) {
    f4 v = reinterpret_cast<const f4*>(kv_ws)[idx];
    bf16x4 w = {(bf16)v.x, (bf16)v.y, (bf16)v.z, (bf16)v.w};
    *(bf16x4*)&kv_b[idx * 4] = w;
  } else if (idx < KV4 + PJ4) {
    int p = idx - KV4;
    int m = p >> 4;
    f4 v = {0.f, 0.f, 0.f, 0.f};
    if (m < MN) v = reinterpret_cast<const f4*>(proj)[p];
    bf16x4 w = {(bf16)v.x, (bf16)v.y, (bf16)v.z, (bf16)v.w};
    *(bf16x4*)&pj_b[p * 4] = w;
  }
}

// ---------------------------------------------------------------------------
// Kernel B (unchanged from round 4, verified): 32x32 MFMA, whole-M LDS-resident
// ---------------------------------------------------------------------------
__global__ __launch_bounds__(512, 2) void perf_out_mfma32(
    const float* __restrict__ qg, const bf16* __restrict__ pjb,
    const bf16* __restrict__ kvb, const float* __restrict__ ksum_ws,
    float* __restrict__ outg)
{
  __shared__ __align__(16) bf16 pj_lds[MP * STR];   // [m][d]   46080 B
  __shared__ __align__(16) bf16 kv_lds[DN * KVS];   // [d][m]   41984 B
  __shared__ __align__(16) float ksum_lds[MP];
  __shared__ float dp_lds[8 * 64];

  const int t    = threadIdx.x;
  const int wid  = t >> 6;
  const int lane = t & 63;
  const int ln31 = lane & 31;
  const int hi   = lane >> 5;
  const int bh   = blockIdx.y;
  const int lbase = blockIdx.x * 1024;

  for (int idx = t; idx < MP * 8; idx += 512) {
    int r = idx >> 3, c8 = idx & 7;
    *(bf16x8*)&pj_lds[r * STR + c8 * 8] = *(const bf16x8*)&pjb[r * 64 + c8 * 8];
  }
  for (int idx = t; idx < DN * 40; idx += 512) {
    int r = idx / 40, cc = idx % 40;
    *(bf16x8*)&kv_lds[r * KVS + cc * 8] =
        *(const bf16x8*)&kvb[((size_t)bh * DN + r) * MP + cc * 8];
  }
  if (t < MP) ksum_lds[t] = ksum_ws[bh * MP + t];
  __syncthreads();  // the only block barrier

  for (int rnd = 0; rnd < 2; ++rnd) {
    const int lw = lbase + rnd * 512 + wid * 64;

    bf16x8 qb[2][4];
#pragma unroll
    for (int lt = 0; lt < 2; ++lt)
#pragma unroll
      for (int ks = 0; ks < 4; ++ks) {
        const float* qp_ = qg + ((size_t)bh * LN + lw + lt * 32 + ln31) * 64 + ks * 16 + hi * 8;
        f4 a = *(const f4*)qp_;
        f4 b = *(const f4*)(qp_ + 4);
        qb[lt][ks] = (bf16x8){(bf16)a.x, (bf16)a.y, (bf16)a.z, (bf16)a.w,
                              (bf16)b.x, (bf16)b.y, (bf16)b.z, (bf16)b.w};
      }

    f32x16 oc[2][2];
    oc[0][0] = (f32x16){}; oc[0][1] = (f32x16){};
    oc[1][0] = (f32x16){}; oc[1][1] = (f32x16){};
    float dp[2] = {0.f, 0.f};

    for (int mc = 0; mc < 5; ++mc) {
      f32x16 c2[2][2];
      c2[0][0] = (f32x16){}; c2[0][1] = (f32x16){};
      c2[1][0] = (f32x16){}; c2[1][1] = (f32x16){};
#pragma unroll
      for (int ks = 0; ks < 4; ++ks) {
        bf16x8 pa0 = *(const bf16x8*)&pj_lds[(mc * 64 + ln31) * STR + ks * 16 + hi * 8];
        bf16x8 pa1 = *(const bf16x8*)&pj_lds[(mc * 64 + 32 + ln31) * STR + ks * 16 + hi * 8];
        c2[0][0] = MFMA32(pa0, qb[0][ks], c2[0][0]);
        c2[1][0] = MFMA32(pa0, qb[1][ks], c2[1][0]);
        c2[0][1] = MFMA32(pa1, qb[0][ks], c2[0][1]);
        c2[1][1] = MFMA32(pa1, qb[1][ks], c2[1][1]);
      }
#pragma unroll
      for (int mt = 0; mt < 2; ++mt) {
        const int mb = mc * 64 + mt * 32 + 4 * hi;
        f32x4 kq0 = *(const f32x4*)&ksum_lds[mb + 0];
        f32x4 kq1 = *(const f32x4*)&ksum_lds[mb + 8];
        f32x4 kq2 = *(const f32x4*)&ksum_lds[mb + 16];
        f32x4 kq3 = *(const f32x4*)&ksum_lds[mb + 24];
        bf16x8 A[2][2];
#pragma unroll
        for (int lt = 0; lt < 2; ++lt) {
          f32x16 f = c2[lt][mt];
#pragma unroll
          for (int i = 0; i < 16; ++i) f[i] = fmaxf(f[i], 0.f) + EPSF;
          dp[lt] += f[0] * kq0[0] + f[1] * kq0[1] + f[2] * kq0[2] + f[3] * kq0[3]
                  + f[4] * kq1[0] + f[5] * kq1[1] + f[6] * kq1[2] + f[7] * kq1[3]
                  + f[8] * kq2[0] + f[9] * kq2[1] + f[10] * kq2[2] + f[11] * kq2[3]
                  + f[12] * kq3[0] + f[13] * kq3[1] + f[14] * kq3[2] + f[15] * kq3[3];
          u32 w0 = cvt_pk_bf16(f[0], f[1]);
          u32 w1 = cvt_pk_bf16(f[2], f[3]);
          u32 w2 = cvt_pk_bf16(f[4], f[5]);
          u32 w3 = cvt_pk_bf16(f[6], f[7]);
          u32 w4 = cvt_pk_bf16(f[8], f[9]);
          u32 w5 = cvt_pk_bf16(f[10], f[11]);
          u32 w6 = cvt_pk_bf16(f[12], f[13]);
          u32 w7 = cvt_pk_bf16(f[14], f[15]);
          asm("v_permlane32_swap_b32 %0, %1" : "+v"(w0), "+v"(w2));
          asm("v_permlane32_swap_b32 %0, %1" : "+v"(w1), "+v"(w3));
          asm("v_permlane32_swap_b32 %0, %1" : "+v"(w4), "+v"(w6));
          asm("v_permlane32_swap_b32 %0, %1" : "+v"(w5), "+v"(w7));
          u32x4 a0 = {w0, w1, w2, w3};
          u32x4 a1 = {w4, w5, w6, w7};
          A[lt][0] = __builtin_bit_cast(bf16x8, a0);
          A[lt][1] = __builtin_bit_cast(bf16x8, a1);
        }
#pragma unroll
        for (int kk = 0; kk < 2; ++kk) {
          const int mo = mc * 64 + (mt * 2 + kk) * 16 + hi * 8;
          bf16x8 kb0 = *(const bf16x8*)&kv_lds[ln31 * KVS + mo];
          bf16x8 kb1 = *(const bf16x8*)&kv_lds[(32 + ln31) * KVS + mo];
          oc[0][0] = MFMA32(A[0][kk], kb0, oc[0][0]);
          oc[1][0] = MFMA32(A[1][kk], kb0, oc[1][0]);
          oc[0][1] = MFMA32(A[0][kk], kb1, oc[0][1]);
          oc[1][1] = MFMA32(A[1][kk], kb1, oc[1][1]);
        }
      }
    }

#pragma unroll
    for (int lt = 0; lt < 2; ++lt) {
      float r = dp[lt];
      r += __shfl_xor(r, 32);
      dp_lds[wid * 64 + lt * 32 + ln31] = r;
    }
#pragma unroll
    for (int lt = 0; lt < 2; ++lt) {
#pragma unroll
      for (int rg = 0; rg < 4; ++rg) {
        f32x4 dv = *(const f32x4*)&dp_lds[wid * 64 + lt * 32 + 8 * rg + 4 * hi];
        f32x4 di = {1.f / dv[0], 1.f / dv[1], 1.f / dv[2], 1.f / dv[3]};
#pragma unroll
        for (int dt = 0; dt < 2; ++dt) {
#pragma unroll
          for (int j = 0; j < 4; ++j) {
            int l = lw + lt * 32 + 8 * rg + 4 * hi + j;
            outg[((size_t)bh * LN + l) * DN + dt * 32 + ln31] = oc[lt][dt][4 * rg + j] * di[j];
          }
        }
      }
    }
  }
}

// ---------------------------------------------------------------------------
extern "C" void kernel_launch(void* const* d_in, const int* in_sizes, int n_in,
                              void* d_out, int out_size, void* d_ws, size_t ws_size,
                              hipStream_t stream)
{
  const float* q    = (const float*)d_in[0];
  const float* k    = (const float*)d_in[1];
  const float* v    = (const float*)d_in[2];
  const float* proj = (const float*)d_in[3];
  float* out     = (float*)d_out;

  float* kv_ws   = (float*)d_ws;                        // [64][64][320] f32
  float* ksum_ws = kv_ws + (size_t)BHN * DN * MP;       // [64][320] f32
  bf16*  kv_b    = (bf16*)(ksum_ws + (size_t)BHN * MP); // [64][64][320] bf16
  bf16*  pj_b    = kv_b + (size_t)BHN * DN * MP;        // [320][64] bf16

  size_t zero_bytes = ((size_t)BHN * DN * MP + (size_t)BHN * MP) * sizeof(float);
  hipMemsetAsync(d_ws, 0, zero_bytes, stream);

  perf_kv_mfma32<<<dim3(8, BHN), 320, 0, stream>>>(k, v, proj, kv_ws, ksum_ws);

  const int CVT_ITEMS = BHN * DN * MP / 4 + MP * DN / 4;
  perf_cvt<<<(CVT_ITEMS + 255) / 256, 256, 0, stream>>>(kv_ws, proj, kv_b, pj_b);

  perf_out_mfma32<<<dim3(4, BHN), 512, 0, stream>>>(q, pj_b, kv_b, ksum_ws, out);
}

// Round 6
// 143.059 us; speedup vs baseline: 1.0585x; 1.0585x over previous
//
#include <hip/hip_runtime.h>

typedef __bf16 bf16;
typedef bf16 bf16x2 __attribute__((ext_vector_type(2)));
typedef bf16 bf16x4 __attribute__((ext_vector_type(4)));
typedef bf16 bf16x8 __attribute__((ext_vector_type(8)));
typedef float f32x4 __attribute__((ext_vector_type(4)));
typedef float f32x16 __attribute__((ext_vector_type(16)));
typedef unsigned int u32;
typedef u32 u32x4 __attribute__((ext_vector_type(4)));
typedef float4 f4;

constexpr int BHN = 64;   // B*H
constexpr int LN  = 4096;
constexpr int DN  = 64;
constexpr int MN  = 266;  // real feature rows
constexpr int MP  = 320;  // padded to 5*64 (workspace only written for m<MN)
constexpr int STR = 72;   // LDS row stride in bf16 (144B, 16B-aligned)
constexpr int KVS = 328;  // kv LDS row stride in bf16 (656B)
#define EPSF 1e-3f

#define MFMA32(A, B, C) __builtin_amdgcn_mfma_f32_32x32x16_bf16(A, B, C, 0, 0, 0)

__device__ __forceinline__ u32 cvt_pk_bf16(float lo, float hi) {
  u32 r;
  asm("v_cvt_pk_bf16_f32 %0, %1, %2" : "=v"(r) : "v"(lo), "v"(hi));
  return r;
}

// ---------------------------------------------------------------------------
// Kernel A v3: r5's 32x32+T12 compute structure, r2's LDS staging structure.
//   kvT[bh][d][m] += V^T·kp,  ksum[bh][m] += sum_l kp,  kp = relu(K·projT)+eps
// grid (8 l-chunks, 64 bh) x 320 threads (5 waves; wave w owns m in [64w,64w+64))
// K and V^T staged in LDS per 64-l tile (coalesced f4). kp stays in registers
// via cvt_pk + permlane32_swap (proven r4/r5). proj register-resident.
// ---------------------------------------------------------------------------
__global__ __launch_bounds__(320, 2) void perf_kv_mfma32(
    const float* __restrict__ kg, const float* __restrict__ vg,
    const float* __restrict__ proj, float* __restrict__ kv_ws,
    float* __restrict__ ksum_ws)
{
  __shared__ __align__(16) bf16 k_lds[64 * STR];   // [l][d]  9216 B
  __shared__ __align__(16) bf16 vt_lds[64 * STR];  // [d][l]  9216 B

  const int t    = threadIdx.x;
  const int wid  = t >> 6;      // 0..4
  const int lane = t & 63;
  const int ln31 = lane & 31;
  const int hi   = lane >> 5;
  const int lsp  = blockIdx.x;  // 0..7
  const int bh   = blockIdx.y;  // 0..63
  const int mw   = wid * 64;

  // proj B-fragments, register-resident: col m = mw+mt*32+ln31, k(d)=ks*16+hi*8+e
  bf16x8 pb[2][4];
#pragma unroll
  for (int mt = 0; mt < 2; ++mt) {
    const int m = mw + mt * 32 + ln31;
#pragma unroll
    for (int ks = 0; ks < 4; ++ks) {
      bf16x8 w = {};
      if (m < MN) {
        const float* p = proj + m * 64 + ks * 16 + hi * 8;
        f4 a = *(const f4*)p;
        f4 b = *(const f4*)(p + 4);
        w = (bf16x8){(bf16)a.x, (bf16)a.y, (bf16)a.z, (bf16)a.w,
                     (bf16)b.x, (bf16)b.y, (bf16)b.z, (bf16)b.w};
      }
      pb[mt][ks] = w;
    }
  }

  f32x16 acc[2][2];  // [dt][mt]: kvT rows d = dt*32+(r&3)+8(r>>2)+4hi, col m
  acc[0][0] = (f32x16){}; acc[0][1] = (f32x16){};
  acc[1][0] = (f32x16){}; acc[1][1] = (f32x16){};
  float ksum_acc[2] = {0.f, 0.f};

  const float* kbase = kg + (size_t)bh * LN * 64;
  const float* vbase = vg + (size_t)bh * LN * 64;

  for (int ls = 0; ls < 8; ++ls) {
    const int l0 = lsp * 512 + ls * 64;
    __syncthreads();  // previous tile fully consumed
    // stage K [64 l][64 d] f32 -> bf16 (coalesced f4)
    for (int idx = t; idx < 1024; idx += 320) {
      int row = idx >> 4, d4 = idx & 15;
      f4 val = *((const f4*)(kbase + (size_t)(l0 + row) * 64) + d4);
      bf16x4 w = {(bf16)val.x, (bf16)val.y, (bf16)val.z, (bf16)val.w};
      *(bf16x4*)&k_lds[row * STR + d4 * 4] = w;
    }
    // stage V^T [64 d][64 l]: f4 reads (coalesced) + 2x4 register transpose
    for (int u = t; u < 512; u += 320) {
      int lb2 = u >> 4, d4 = u & 15;
      const float* vp = vbase + (size_t)(l0 + lb2 * 2) * 64 + d4 * 4;
      f4 a = *(const f4*)vp;
      f4 b = *(const f4*)(vp + 64);
      bf16x2 w0 = {(bf16)a.x, (bf16)b.x};
      bf16x2 w1 = {(bf16)a.y, (bf16)b.y};
      bf16x2 w2 = {(bf16)a.z, (bf16)b.z};
      bf16x2 w3 = {(bf16)a.w, (bf16)b.w};
      *(bf16x2*)&vt_lds[(d4 * 4 + 0) * STR + lb2 * 2] = w0;
      *(bf16x2*)&vt_lds[(d4 * 4 + 1) * STR + lb2 * 2] = w1;
      *(bf16x2*)&vt_lds[(d4 * 4 + 2) * STR + lb2 * 2] = w2;
      *(bf16x2*)&vt_lds[(d4 * 4 + 3) * STR + lb2 * 2] = w3;
    }
    __syncthreads();  // tile ready

#pragma unroll
    for (int lt = 0; lt < 2; ++lt) {
      // K A-fragments: row l = l0+lt*32+ln31, k(d) = ks*16+hi*8+e
      bf16x8 ka[4];
#pragma unroll
      for (int ks = 0; ks < 4; ++ks)
        ka[ks] = *(const bf16x8*)&k_lds[(lt * 32 + ln31) * STR + ks * 16 + hi * 8];
      // V^T A-fragments: row d = dt*32+ln31, k(l) = lt*32+kk*16+hi*8+e
      bf16x8 va[2][2];
#pragma unroll
      for (int dt = 0; dt < 2; ++dt)
#pragma unroll
        for (int kk = 0; kk < 2; ++kk)
          va[dt][kk] = *(const bf16x8*)&vt_lds[(dt * 32 + ln31) * STR + lt * 32 + kk * 16 + hi * 8];

#pragma unroll
      for (int mt = 0; mt < 2; ++mt) {
        // feature: C1[l][m] = K·projT (lane = m-col, regs = l-rows)
        f32x16 f = (f32x16){};
#pragma unroll
        for (int ks = 0; ks < 4; ++ks) f = MFMA32(ka[ks], pb[mt][ks], f);
#pragma unroll
        for (int i = 0; i < 16; ++i) f[i] = fmaxf(f[i], 0.f) + EPSF;
        ksum_acc[mt] += f[0] + f[1] + f[2] + f[3] + f[4] + f[5] + f[6] + f[7]
                      + f[8] + f[9] + f[10] + f[11] + f[12] + f[13] + f[14] + f[15];
        // T12: pack to bf16 words, permlane-swap into B-operand (col=m, k=l)
        u32 w0 = cvt_pk_bf16(f[0], f[1]);
        u32 w1 = cvt_pk_bf16(f[2], f[3]);
        u32 w2 = cvt_pk_bf16(f[4], f[5]);
        u32 w3 = cvt_pk_bf16(f[6], f[7]);
        u32 w4 = cvt_pk_bf16(f[8], f[9]);
        u32 w5 = cvt_pk_bf16(f[10], f[11]);
        u32 w6 = cvt_pk_bf16(f[12], f[13]);
        u32 w7 = cvt_pk_bf16(f[14], f[15]);
        asm("v_permlane32_swap_b32 %0, %1" : "+v"(w0), "+v"(w2));
        asm("v_permlane32_swap_b32 %0, %1" : "+v"(w1), "+v"(w3));
        asm("v_permlane32_swap_b32 %0, %1" : "+v"(w4), "+v"(w6));
        asm("v_permlane32_swap_b32 %0, %1" : "+v"(w5), "+v"(w7));
        u32x4 a0 = {w0, w1, w2, w3};
        u32x4 a1 = {w4, w5, w6, w7};
        bf16x8 kb0 = __builtin_bit_cast(bf16x8, a0);  // k = l rel 0..15
        bf16x8 kb1 = __builtin_bit_cast(bf16x8, a1);  // k = l rel 16..31
        acc[0][mt] = MFMA32(va[0][0], kb0, acc[0][mt]);
        acc[1][mt] = MFMA32(va[1][0], kb0, acc[1][mt]);
        acc[0][mt] = MFMA32(va[0][1], kb1, acc[0][mt]);
        acc[1][mt] = MFMA32(va[1][1], kb1, acc[1][mt]);
      }
    }
  }

  // epilogue: f32 atomics into workspace (guarded: padded m stays exactly 0)
#pragma unroll
  for (int mt = 0; mt < 2; ++mt) {
    const int m = mw + mt * 32 + ln31;
    if (m < MN) {
#pragma unroll
      for (int dt = 0; dt < 2; ++dt) {
#pragma unroll
        for (int r = 0; r < 16; ++r) {
          const int d = dt * 32 + (r & 3) + 8 * (r >> 2) + 4 * hi;
          atomicAdd(&kv_ws[((size_t)bh * 64 + d) * MP + m], acc[dt][mt][r]);
        }
      }
    }
    float r = ksum_acc[mt];
    r += __shfl_xor(r, 32);
    if (hi == 0 && m < MN) atomicAdd(&ksum_ws[bh * MP + m], r);
  }
}

// ---------------------------------------------------------------------------
// Kernel C: one-shot f32 -> bf16 conversion of kv workspace and proj
// ---------------------------------------------------------------------------
__global__ __launch_bounds__(256) void perf_cvt(
    const float* __restrict__ kv_ws, const float* __restrict__ proj,
    bf16* __restrict__ kv_b, bf16* __restrict__ pj_b)
{
  const int KV4 = BHN * DN * MP / 4;  // 327680
  const int PJ4 = MP * DN / 4;        // 5120
  int idx = blockIdx.x * 256 + threadIdx.x;
  if (idx < KV4) {
    f4 v = reinterpret_cast<const f4*>(kv_ws)[idx];
    bf16x4 w = {(bf16)v.x, (bf16)v.y, (bf16)v.z, (bf16)v.w};
    *(bf16x4*)&kv_b[idx * 4] = w;
  } else if (idx < KV4 + PJ4) {
    int p = idx - KV4;
    int m = p >> 4;
    f4 v = {0.f, 0.f, 0.f, 0.f};
    if (m < MN) v = reinterpret_cast<const f4*>(proj)[p];
    bf16x4 w = {(bf16)v.x, (bf16)v.y, (bf16)v.z, (bf16)v.w};
    *(bf16x4*)&pj_b[p * 4] = w;
  }
}

// ---------------------------------------------------------------------------
// Kernel B (unchanged from round 4, verified): 32x32 MFMA, whole-M LDS-resident
// ---------------------------------------------------------------------------
__global__ __launch_bounds__(512, 2) void perf_out_mfma32(
    const float* __restrict__ qg, const bf16* __restrict__ pjb,
    const bf16* __restrict__ kvb, const float* __restrict__ ksum_ws,
    float* __restrict__ outg)
{
  __shared__ __align__(16) bf16 pj_lds[MP * STR];   // [m][d]   46080 B
  __shared__ __align__(16) bf16 kv_lds[DN * KVS];   // [d][m]   41984 B
  __shared__ __align__(16) float ksum_lds[MP];
  __shared__ float dp_lds[8 * 64];

  const int t    = threadIdx.x;
  const int wid  = t >> 6;
  const int lane = t & 63;
  const int ln31 = lane & 31;
  const int hi   = lane >> 5;
  const int bh   = blockIdx.y;
  const int lbase = blockIdx.x * 1024;

  for (int idx = t; idx < MP * 8; idx += 512) {
    int r = idx >> 3, c8 = idx & 7;
    *(bf16x8*)&pj_lds[r * STR + c8 * 8] = *(const bf16x8*)&pjb[r * 64 + c8 * 8];
  }
  for (int idx = t; idx < DN * 40; idx += 512) {
    int r = idx / 40, cc = idx % 40;
    *(bf16x8*)&kv_lds[r * KVS + cc * 8] =
        *(const bf16x8*)&kvb[((size_t)bh * DN + r) * MP + cc * 8];
  }
  if (t < MP) ksum_lds[t] = ksum_ws[bh * MP + t];
  __syncthreads();  // the only block barrier

  for (int rnd = 0; rnd < 2; ++rnd) {
    const int lw = lbase + rnd * 512 + wid * 64;

    bf16x8 qb[2][4];
#pragma unroll
    for (int lt = 0; lt < 2; ++lt)
#pragma unroll
      for (int ks = 0; ks < 4; ++ks) {
        const float* qp_ = qg + ((size_t)bh * LN + lw + lt * 32 + ln31) * 64 + ks * 16 + hi * 8;
        f4 a = *(const f4*)qp_;
        f4 b = *(const f4*)(qp_ + 4);
        qb[lt][ks] = (bf16x8){(bf16)a.x, (bf16)a.y, (bf16)a.z, (bf16)a.w,
                              (bf16)b.x, (bf16)b.y, (bf16)b.z, (bf16)b.w};
      }

    f32x16 oc[2][2];
    oc[0][0] = (f32x16){}; oc[0][1] = (f32x16){};
    oc[1][0] = (f32x16){}; oc[1][1] = (f32x16){};
    float dp[2] = {0.f, 0.f};

    for (int mc = 0; mc < 5; ++mc) {
      f32x16 c2[2][2];
      c2[0][0] = (f32x16){}; c2[0][1] = (f32x16){};
      c2[1][0] = (f32x16){}; c2[1][1] = (f32x16){};
#pragma unroll
      for (int ks = 0; ks < 4; ++ks) {
        bf16x8 pa0 = *(const bf16x8*)&pj_lds[(mc * 64 + ln31) * STR + ks * 16 + hi * 8];
        bf16x8 pa1 = *(const bf16x8*)&pj_lds[(mc * 64 + 32 + ln31) * STR + ks * 16 + hi * 8];
        c2[0][0] = MFMA32(pa0, qb[0][ks], c2[0][0]);
        c2[1][0] = MFMA32(pa0, qb[1][ks], c2[1][0]);
        c2[0][1] = MFMA32(pa1, qb[0][ks], c2[0][1]);
        c2[1][1] = MFMA32(pa1, qb[1][ks], c2[1][1]);
      }
#pragma unroll
      for (int mt = 0; mt < 2; ++mt) {
        const int mb = mc * 64 + mt * 32 + 4 * hi;
        f32x4 kq0 = *(const f32x4*)&ksum_lds[mb + 0];
        f32x4 kq1 = *(const f32x4*)&ksum_lds[mb + 8];
        f32x4 kq2 = *(const f32x4*)&ksum_lds[mb + 16];
        f32x4 kq3 = *(const f32x4*)&ksum_lds[mb + 24];
        bf16x8 A[2][2];
#pragma unroll
        for (int lt = 0; lt < 2; ++lt) {
          f32x16 f = c2[lt][mt];
#pragma unroll
          for (int i = 0; i < 16; ++i) f[i] = fmaxf(f[i], 0.f) + EPSF;
          dp[lt] += f[0] * kq0[0] + f[1] * kq0[1] + f[2] * kq0[2] + f[3] * kq0[3]
                  + f[4] * kq1[0] + f[5] * kq1[1] + f[6] * kq1[2] + f[7] * kq1[3]
                  + f[8] * kq2[0] + f[9] * kq2[1] + f[10] * kq2[2] + f[11] * kq2[3]
                  + f[12] * kq3[0] + f[13] * kq3[1] + f[14] * kq3[2] + f[15] * kq3[3];
          u32 w0 = cvt_pk_bf16(f[0], f[1]);
          u32 w1 = cvt_pk_bf16(f[2], f[3]);
          u32 w2 = cvt_pk_bf16(f[4], f[5]);
          u32 w3 = cvt_pk_bf16(f[6], f[7]);
          u32 w4 = cvt_pk_bf16(f[8], f[9]);
          u32 w5 = cvt_pk_bf16(f[10], f[11]);
          u32 w6 = cvt_pk_bf16(f[12], f[13]);
          u32 w7 = cvt_pk_bf16(f[14], f[15]);
          asm("v_permlane32_swap_b32 %0, %1" : "+v"(w0), "+v"(w2));
          asm("v_permlane32_swap_b32 %0, %1" : "+v"(w1), "+v"(w3));
          asm("v_permlane32_swap_b32 %0, %1" : "+v"(w4), "+v"(w6));
          asm("v_permlane32_swap_b32 %0, %1" : "+v"(w5), "+v"(w7));
          u32x4 a0 = {w0, w1, w2, w3};
          u32x4 a1 = {w4, w5, w6, w7};
          A[lt][0] = __builtin_bit_cast(bf16x8, a0);
          A[lt][1] = __builtin_bit_cast(bf16x8, a1);
        }
#pragma unroll
        for (int kk = 0; kk < 2; ++kk) {
          const int mo = mc * 64 + (mt * 2 + kk) * 16 + hi * 8;
          bf16x8 kb0 = *(const bf16x8*)&kv_lds[ln31 * KVS + mo];
          bf16x8 kb1 = *(const bf16x8*)&kv_lds[(32 + ln31) * KVS + mo];
          oc[0][0] = MFMA32(A[0][kk], kb0, oc[0][0]);
          oc[1][0] = MFMA32(A[1][kk], kb0, oc[1][0]);
          oc[0][1] = MFMA32(A[0][kk], kb1, oc[0][1]);
          oc[1][1] = MFMA32(A[1][kk], kb1, oc[1][1]);
        }
      }
    }

#pragma unroll
    for (int lt = 0; lt < 2; ++lt) {
      float r = dp[lt];
      r += __shfl_xor(r, 32);
      dp_lds[wid * 64 + lt * 32 + ln31] = r;
    }
#pragma unroll
    for (int lt = 0; lt < 2; ++lt) {
#pragma unroll
      for (int rg = 0; rg < 4; ++rg) {
        f32x4 dv = *(const f32x4*)&dp_lds[wid * 64 + lt * 32 + 8 * rg + 4 * hi];
        f32x4 di = {1.f / dv[0], 1.f / dv[1], 1.f / dv[2], 1.f / dv[3]};
#pragma unroll
        for (int dt = 0; dt < 2; ++dt) {
#pragma unroll
          for (int j = 0; j < 4; ++j) {
            int l = lw + lt * 32 + 8 * rg + 4 * hi + j;
            outg[((size_t)bh * LN + l) * DN + dt * 32 + ln31] = oc[lt][dt][4 * rg + j] * di[j];
          }
        }
      }
    }
  }
}

// ---------------------------------------------------------------------------
extern "C" void kernel_launch(void* const* d_in, const int* in_sizes, int n_in,
                              void* d_out, int out_size, void* d_ws, size_t ws_size,
                              hipStream_t stream)
{
  const float* q    = (const float*)d_in[0];
  const float* k    = (const float*)d_in[1];
  const float* v    = (const float*)d_in[2];
  const float* proj = (const float*)d_in[3];
  float* out     = (float*)d_out;

  float* kv_ws   = (float*)d_ws;                        // [64][64][320] f32
  float* ksum_ws = kv_ws + (size_t)BHN * DN * MP;       // [64][320] f32
  bf16*  kv_b    = (bf16*)(ksum_ws + (size_t)BHN * MP); // [64][64][320] bf16
  bf16*  pj_b    = kv_b + (size_t)BHN * DN * MP;        // [320][64] bf16

  size_t zero_bytes = ((size_t)BHN * DN * MP + (size_t)BHN * MP) * sizeof(float);
  hipMemsetAsync(d_ws, 0, zero_bytes, stream);

  perf_kv_mfma32<<<dim3(8, BHN), 320, 0, stream>>>(k, v, proj, kv_ws, ksum_ws);

  const int CVT_ITEMS = BHN * DN * MP / 4 + MP * DN / 4;
  perf_cvt<<<(CVT_ITEMS + 255) / 256, 256, 0, stream>>>(kv_ws, proj, kv_b, pj_b);

  perf_out_mfma32<<<dim3(LN / 1024, BHN), 512, 0, stream>>>(q, pj_b, kv_b, ksum_ws, out);
}